// Round 18
// baseline (161.831 us; speedup 1.0000x reference)
//
#include <hip/hip_runtime.h>

// Navier-Stokes physics-informed loss (f32 in, scalar f32 out).
// x,y: (64,3,512,512). Interior: b in [1,62], i,j in [1,510].
// r0 = |dudx + dvdy| ; r1 = |dudt + u*dudx + v*dudy + dpdx - MU*lap u| ;
// r2 = |dvdt + u*dvdx + v*dvdy + dpdy - MU*lap v| ; dudt=(u[b+1]-u[b-1])*32
//
// Occupancy attribution (R14/R15/R17): time tracks waves/CU (16->145us,
// 12->159us). LDS slab size caps blocks/CU.
// R18: dbuf + single barrier (R17) but stage ONLY u,v (already in chain
// regs -> staging free). p i+-1 rows from global each iter (+16B/pt);
// p center stays a carried reg for the j-shfl. LDS = 32 KiB EXACTLY
// (reduction scratch folded into the slab) -> 5 blocks x 4 waves =
// 20 waves/CU. Grid 1280 = 5 b-chunks x 2 j-halves x 128 bands.

constexpr int Wd   = 512;
constexpr int CSTR = 512 * 512;
constexpr int BSTR = 3 * 512 * 512;

__device__ __forceinline__ float4 ld4(const float* p) {
    return *reinterpret_cast<const float4*>(p);
}
__device__ __forceinline__ float4 scale4(float4 a, float s) {
    return make_float4(a.x * s, a.y * s, a.z * s, a.w * s);
}

// Residuals for one tensor at plane k.
// L: this tensor's current slab [field u,v][row 0..3][256] (scaled).
// eu,ev: band-edge neighbor row (io 0 -> i-1, io 3 -> i+1), scaled.
// um,uc,un / vm,vc,vn: scaled b-chain. pc: RAW carried p center row.
// pxp4,pxm4: RAW p rows i+1 / i-1 (fresh global loads).
// uL..pR: j-boundary scalars for lanes jt 0/63 (u,v scaled; p raw).
__device__ __forceinline__ void plane_resid(
    const float (&L)[2][4][256],
    int io, int jt, int jl,
    float4 eu, float4 ev,
    float4 um, float4 uc, float4 un,
    float4 vm, float4 vc, float4 vn,
    float4 pc, float4 pxp4, float4 pxm4,
    float uL, float vL, float pL,
    float uR, float vR, float pR,
    float sdx,
    float r0[4], float r1[4], float r2[4])
{
    float4 uxm, vxm, uxp, vxp;
    if (io == 0) { uxm = eu; vxm = ev; }
    else {
        uxm = ld4(&L[0][io - 1][jl]);
        vxm = ld4(&L[1][io - 1][jl]);
    }
    if (io == 3) { uxp = eu; vxp = ev; }
    else {
        uxp = ld4(&L[0][io + 1][jl]);
        vxp = ld4(&L[1][io + 1][jl]);
    }

    // j+-1 via lane+-1 shfl on carried regs; boundary lanes use scalars.
    float u_l = __shfl_up(uc.w, 1);
    float v_l = __shfl_up(vc.w, 1);
    float p_l = __shfl_up(pc.w, 1);
    float u_r = __shfl_down(uc.x, 1);
    float v_r = __shfl_down(vc.x, 1);
    float p_r = __shfl_down(pc.x, 1);
    if (jt == 0)  { u_l = uL; v_l = vL; p_l = pL; }
    if (jt == 63) { u_r = uR; v_r = vR; p_r = pR; }

    const float ucA[4] = {uc.x, uc.y, uc.z, uc.w};
    const float vcA[4] = {vc.x, vc.y, vc.z, vc.w};
    const float umA[4] = {um.x, um.y, um.z, um.w};
    const float vmA[4] = {vm.x, vm.y, vm.z, vm.w};
    const float unA[4] = {un.x, un.y, un.z, un.w};
    const float vnA[4] = {vn.x, vn.y, vn.z, vn.w};
    const float ul[4]  = {u_l, uc.x, uc.y, uc.z};
    const float ur[4]  = {uc.y, uc.z, uc.w, u_r};
    const float vl[4]  = {v_l, vc.x, vc.y, vc.z};
    const float vr[4]  = {vc.y, vc.z, vc.w, v_r};
    const float pl[4]  = {p_l, pc.x, pc.y, pc.z};
    const float pr[4]  = {pc.y, pc.z, pc.w, p_r};
    const float uxpA[4] = {uxp.x, uxp.y, uxp.z, uxp.w};
    const float uxmA[4] = {uxm.x, uxm.y, uxm.z, uxm.w};
    const float vxpA[4] = {vxp.x, vxp.y, vxp.z, vxp.w};
    const float vxmA[4] = {vxm.x, vxm.y, vxm.z, vxm.w};
    const float pxpA[4] = {pxp4.x, pxp4.y, pxp4.z, pxp4.w};
    const float pxmA[4] = {pxm4.x, pxm4.y, pxm4.z, pxm4.w};

    #pragma unroll
    for (int k = 0; k < 4; ++k) {
        const float dudx = (uxpA[k] - uxmA[k]) * 127.5f;   // scaled inputs
        const float dvdx = (vxpA[k] - vxmA[k]) * 127.5f;
        const float dpdx = (pxpA[k] - pxmA[k]) * sdx;      // raw p
        const float dudy = (ur[k] - ul[k]) * 127.5f;
        const float dvdy = (vr[k] - vl[k]) * 127.5f;
        const float dpdy = (pr[k] - pl[k]) * sdx;
        const float lapu = (uxpA[k] + uxmA[k] + ur[k] + ul[k]) * 0.65025f
                         - 2.601f * ucA[k];
        const float lapv = (vxpA[k] + vxmA[k] + vr[k] + vl[k]) * 0.65025f
                         - 2.601f * vcA[k];
        r0[k] = fabsf(dudx + dvdy);
        r1[k] = fabsf((unA[k] - umA[k]) * 32.0f + ucA[k] * dudx + vcA[k] * dudy
                      + dpdx - lapu);
        r2[k] = fabsf((vnA[k] - vmA[k]) * 32.0f + ucA[k] * dvdx + vcA[k] * dvdy
                      + dpdy - lapv);
    }
}

__global__ __launch_bounds__(256)
void ns_loss_kernel(const float* __restrict__ X, const float* __restrict__ Y,
                    const float* __restrict__ stdp, double* __restrict__ acc)
{
    // [buf][tensor][field u,v][row][col] = 32768 B exactly.
    // Reduction scratch reuses this slab post-loop.
    __shared__ float lds[2][2][2][4][256];

    const float s   = *stdp;
    const float sdx = s * 127.5f;

    // Swizzle: nwg = 1280; XCD k owns 160 contiguous work ids
    // (z-major, jh, band-minor) -> i-contiguity within each XCD's L2.
    const int orig = blockIdx.x;
    const int wg   = (orig & 7) * 160 + (orig >> 3);
    const int z    = wg >> 8;              // b-chunk 0..4
    const int rem  = wg & 255;
    const int jh   = rem >> 7;             // j-half
    const int band = rem & 127;            // i-band

    const int tid = threadIdx.x;
    const int io  = tid >> 6;              // row in band (wave-uniform)
    const int jt  = tid & 63;              // f4-col in half-row
    const int jl  = jt << 2;               // 0..252
    const int j0g = (jh << 8) + jl;        // global float col
    const int irow = 1 + band * 4 + io;
    const int i    = min(irow, 511);
    const bool vrow = (irow <= 510);
    const int bs     = (z < 2) ? (1 + 13 * z) : (27 + 12 * (z - 2)); // 1,14,27,39,51
    const int nsteps = (z < 2) ? 13 : 12;

    int c = bs * BSTR + i * Wd + j0g;
    const int eoff = (io == 0) ? -Wd : ((i < 511) ? Wd : 0);
    const bool isedge = (io == 0) || (io == 3);
    const int offL = (j0g == 0) ? 0 : -1;            // clamped; masked at k=0
    const int offR = (j0g == 508) ? 3 : 4;           // clamped; masked at k=3

    // ---- prologue: chains at plane bs ----
    float4 xum = scale4(ld4(X + c - BSTR), s);
    float4 xuc = scale4(ld4(X + c), s);
    float4 xun = scale4(ld4(X + c + BSTR), s);
    float4 xvm = scale4(ld4(X + c - BSTR + CSTR), s);
    float4 xvc = scale4(ld4(X + c + CSTR), s);
    float4 xvn = scale4(ld4(X + c + BSTR + CSTR), s);
    float4 xpc = ld4(X + c + 2 * CSTR);              // raw p center
    float4 yum = scale4(ld4(Y + c - BSTR), s);
    float4 yuc = scale4(ld4(Y + c), s);
    float4 yun = scale4(ld4(Y + c + BSTR), s);
    float4 yvm = scale4(ld4(Y + c - BSTR + CSTR), s);
    float4 yvc = scale4(ld4(Y + c + CSTR), s);
    float4 yvn = scale4(ld4(Y + c + BSTR + CSTR), s);
    float4 ypc = ld4(Y + c + 2 * CSTR);
    float4 xpn = ld4(X + c + 2 * CSTR + BSTR);       // p at plane+1
    float4 ypn = ld4(Y + c + 2 * CSTR + BSTR);

    // stage plane 0 u,v into buf 0
    *(float4*)&lds[0][0][0][io][jl] = xuc;
    *(float4*)&lds[0][0][1][io][jl] = xvc;
    *(float4*)&lds[0][1][0][io][jl] = yuc;
    *(float4*)&lds[0][1][1][io][jl] = yvc;
    __syncthreads();

    float s0 = 0.0f, s1 = 0.0f, s2 = 0.0f;

    for (int k = 0; k < nsteps; ++k) {
        const int cur = k & 1;

        // ---- fresh loads for plane k: p i+-1 (always), u,v edges (io 0/3) ----
        const float4 xpxp = ld4(X + c + 2 * CSTR + Wd);
        const float4 xpxm = ld4(X + c + 2 * CSTR - Wd);
        const float4 ypxp = ld4(Y + c + 2 * CSTR + Wd);
        const float4 ypxm = ld4(Y + c + 2 * CSTR - Wd);
        float4 xeu = make_float4(0, 0, 0, 0), xev = xeu;
        float4 yeu = xeu, yev = xeu;
        if (isedge) {
            xeu = scale4(ld4(X + c + eoff), s);
            xev = scale4(ld4(X + c + CSTR + eoff), s);
            yeu = scale4(ld4(Y + c + eoff), s);
            yev = scale4(ld4(Y + c + CSTR + eoff), s);
        }
        float xuL = 0, xvL = 0, xpL = 0, yuL = 0, yvL = 0, ypL = 0;
        float xuR = 0, xvR = 0, xpR = 0, yuR = 0, yvR = 0, ypR = 0;
        if (jt == 0) {
            xuL = X[c + offL] * s; xvL = X[c + CSTR + offL] * s;
            xpL = X[c + 2 * CSTR + offL];
            yuL = Y[c + offL] * s; yvL = Y[c + CSTR + offL] * s;
            ypL = Y[c + 2 * CSTR + offL];
        }
        if (jt == 63) {
            xuR = X[c + offR] * s; xvR = X[c + CSTR + offR] * s;
            xpR = X[c + 2 * CSTR + offR];
            yuR = Y[c + offR] * s; yvR = Y[c + CSTR + offR] * s;
            ypR = Y[c + 2 * CSTR + offR];
        }

        // ---- compute plane k ----
        float r0x[4], r1x[4], r2x[4], r0y[4], r1y[4], r2y[4];
        plane_resid(lds[cur][0], io, jt, jl, xeu, xev,
                    xum, xuc, xun, xvm, xvc, xvn, xpc, xpxp, xpxm,
                    xuL, xvL, xpL, xuR, xvR, xpR, sdx, r0x, r1x, r2x);
        plane_resid(lds[cur][1], io, jt, jl, yeu, yev,
                    yum, yuc, yun, yvm, yvc, yvn, ypc, ypxp, ypxm,
                    yuL, yvL, ypL, yuR, yvR, ypR, sdx, r0y, r1y, r2y);

        #pragma unroll
        for (int kk = 0; kk < 4; ++kk) {
            float e0 = r0y[kk] - r0x[kk];
            float e1 = r1y[kk] - r1x[kk];
            float e2 = r2y[kk] - r2x[kk];
            const bool dead = (!vrow) || (kk == 0 && j0g == 0)
                                      || (kk == 3 && j0g == 508);
            if (dead) { e0 = 0.0f; e1 = 0.0f; e2 = 0.0f; }
            s0 += e0 * e0; s1 += e1 * e1; s2 += e2 * e2;
        }

        // ---- stage plane k+1 u,v (chain regs) into buf[cur^1] ----
        *(float4*)&lds[cur ^ 1][0][0][io][jl] = xun;
        *(float4*)&lds[cur ^ 1][0][1][io][jl] = xvn;
        *(float4*)&lds[cur ^ 1][1][0][io][jl] = yun;
        *(float4*)&lds[cur ^ 1][1][1][io][jl] = yvn;

        // ---- chain prefetch: plane k+2 (clamped to k+1 on last iter) ----
        const int pfo = (k + 1 < nsteps) ? 2 * BSTR : BSTR;
        const float4 xu2 = scale4(ld4(X + c + pfo), s);
        const float4 xv2 = scale4(ld4(X + c + pfo + CSTR), s);
        const float4 xp2 = ld4(X + c + pfo + 2 * CSTR);
        const float4 yu2 = scale4(ld4(Y + c + pfo), s);
        const float4 yv2 = scale4(ld4(Y + c + pfo + CSTR), s);
        const float4 yp2 = ld4(Y + c + pfo + 2 * CSTR);

        // ---- rotate chains ----
        xum = xuc; xuc = xun; xun = xu2;
        xvm = xvc; xvc = xvn; xvn = xv2;
        xpc = xpn; xpn = xp2;
        yum = yuc; yuc = yun; yun = yu2;
        yvm = yvc; yvc = yvn; yvn = yv2;
        ypc = ypn; ypn = yp2;

        // ---- single barrier; global prefetches stay in flight ----
        asm volatile("s_waitcnt lgkmcnt(0)" ::: "memory");
        __builtin_amdgcn_s_barrier();
        c += BSTR;
    }

    // ---- reduction: wave shuffle -> LDS (reused slab) -> f64 atomic ----
    for (int o = 32; o > 0; o >>= 1) {
        s0 += __shfl_down(s0, o);
        s1 += __shfl_down(s1, o);
        s2 += __shfl_down(s2, o);
    }
    float* red = &lds[0][0][0][0][0];     // safe: all LDS reads done pre-barrier
    const int wid = tid >> 6;
    if (jt == 0) { red[wid] = s0; red[4 + wid] = s1; red[8 + wid] = s2; }
    __syncthreads();
    if (tid == 0) {
        atomicAdd(&acc[0], (double)red[0] + (double)red[1]
                         + (double)red[2] + (double)red[3]);
        atomicAdd(&acc[1], (double)red[4] + (double)red[5]
                         + (double)red[6] + (double)red[7]);
        atomicAdd(&acc[2], (double)red[8] + (double)red[9]
                         + (double)red[10] + (double)red[11]);
    }
}

__global__ void ns_finalize_kernel(const double* __restrict__ acc,
                                   float* __restrict__ out)
{
    if (threadIdx.x == 0) {
        const double N = 62.0 * 510.0 * 510.0;
        out[0] = (float)(1.0e-3 * (acc[0] + acc[1] + acc[2]) / N);
    }
}

extern "C" void kernel_launch(void* const* d_in, const int* in_sizes, int n_in,
                              void* d_out, int out_size, void* d_ws, size_t ws_size,
                              hipStream_t stream) {
    const float* X    = (const float*)d_in[0];
    const float* Y    = (const float*)d_in[1];
    const float* stdp = (const float*)d_in[2];
    float* out  = (float*)d_out;
    double* acc = (double*)d_ws;

    hipMemsetAsync(acc, 0, 3 * sizeof(double), stream);

    dim3 block(256);
    dim3 grid(1280);  // 5 b-chunks x 2 j-halves x 128 bands; 5 blocks/CU
    ns_loss_kernel<<<grid, block, 0, stream>>>(X, Y, stdp, acc);
    ns_finalize_kernel<<<1, 64, 0, stream>>>(acc, out);
}

// Round 19
// 140.619 us; speedup vs baseline: 1.1509x; 1.1509x over previous
//
#include <hip/hip_runtime.h>

// Navier-Stokes physics-informed loss (f32 in, scalar f32 out).
// x,y: (64,3,512,512). Interior: b in [1,62], i,j in [1,510].
// r0 = |dudx + dvdy| ; r1 = |dudt + u*dudx + v*dudy + dpdx - MU*lap u| ;
// r2 = |dvdt + u*dvdx + v*dvdy + dpdy - MU*lap v| ; dudt=(u[b+1]-u[b-1])*32
//
// R4-R18 law: occupancy tiers at VGPR 64/128 (m69); every fused-XY kernel
// sits at VGPR 76-112 -> 16 waves/CU hard cap; best = R14 (wall 124us).
// R19: WAVE-SPECIALIZED X/Y SPLIT to reach the 8-waves/SIMD tier.
// Block = 512 thr: waves 0-3 own X, waves 4-7 own Y (same tile). One
// tensor per thread -> carried regs ~20 (um,uc,vm,vc,pc; un/vn/pn fresh,
// un->uc rotation). Cross-tensor (r_y-r_x)^2 via 12KiB LDS exchange:
// X-waves write r, barrier, Y-waves subtract+accumulate.
// LDS 36KiB: stage[2][3][4][256] 24K + rxch[3][4][256] 12K.
// If VGPR<=64: 4 blocks/CU = 32 waves/CU (2x R14). If 65-128: exactly
// R14 residency (1024 blocks = clean 2 rounds, no tail).

constexpr int Wd   = 512;
constexpr int CSTR = 512 * 512;
constexpr int BSTR = 3 * 512 * 512;

__device__ __forceinline__ float4 ld4(const float* p) {
    return *reinterpret_cast<const float4*>(p);
}
__device__ __forceinline__ float4 scale4(float4 a, float s) {
    return make_float4(a.x * s, a.y * s, a.z * s, a.w * s);
}

// Residuals for ONE tensor at the current plane.
// L: this tensor's stage slab [u,v,p][row 0..3][256] (u,v scaled; p raw).
// eu,ev (scaled), ep (raw): band-edge neighbor row (io 0 -> i-1, io 3 -> i+1).
// um,uc,un / vm,vc,vn: scaled b-chain (b-1, b, b+1). pc: raw p center row.
// uL..pR: j-boundary scalars for lanes jt 0/63.
__device__ __forceinline__ void plane_resid(
    const float (&L)[3][4][256],
    int io, int jt, int jl,
    float4 eu, float4 ev, float4 ep,
    float4 um, float4 uc, float4 un,
    float4 vm, float4 vc, float4 vn,
    float4 pc,
    float uL, float vL, float pL,
    float uR, float vR, float pR,
    float sdx,
    float r0[4], float r1[4], float r2[4])
{
    float4 uxm, vxm, pxm, uxp, vxp, pxp;
    if (io == 0) { uxm = eu; vxm = ev; pxm = ep; }
    else {
        uxm = ld4(&L[0][io - 1][jl]);
        vxm = ld4(&L[1][io - 1][jl]);
        pxm = ld4(&L[2][io - 1][jl]);
    }
    if (io == 3) { uxp = eu; vxp = ev; pxp = ep; }
    else {
        uxp = ld4(&L[0][io + 1][jl]);
        vxp = ld4(&L[1][io + 1][jl]);
        pxp = ld4(&L[2][io + 1][jl]);
    }

    // j+-1 via lane+-1 shfl on carried regs; boundary lanes use scalars.
    float u_l = __shfl_up(uc.w, 1);
    float v_l = __shfl_up(vc.w, 1);
    float p_l = __shfl_up(pc.w, 1);
    float u_r = __shfl_down(uc.x, 1);
    float v_r = __shfl_down(vc.x, 1);
    float p_r = __shfl_down(pc.x, 1);
    if (jt == 0)  { u_l = uL; v_l = vL; p_l = pL; }
    if (jt == 63) { u_r = uR; v_r = vR; p_r = pR; }

    const float ucA[4] = {uc.x, uc.y, uc.z, uc.w};
    const float vcA[4] = {vc.x, vc.y, vc.z, vc.w};
    const float umA[4] = {um.x, um.y, um.z, um.w};
    const float vmA[4] = {vm.x, vm.y, vm.z, vm.w};
    const float unA[4] = {un.x, un.y, un.z, un.w};
    const float vnA[4] = {vn.x, vn.y, vn.z, vn.w};
    const float ul[4]  = {u_l, uc.x, uc.y, uc.z};
    const float ur[4]  = {uc.y, uc.z, uc.w, u_r};
    const float vl[4]  = {v_l, vc.x, vc.y, vc.z};
    const float vr[4]  = {vc.y, vc.z, vc.w, v_r};
    const float pl[4]  = {p_l, pc.x, pc.y, pc.z};
    const float pr[4]  = {pc.y, pc.z, pc.w, p_r};
    const float uxpA[4] = {uxp.x, uxp.y, uxp.z, uxp.w};
    const float uxmA[4] = {uxm.x, uxm.y, uxm.z, uxm.w};
    const float vxpA[4] = {vxp.x, vxp.y, vxp.z, vxp.w};
    const float vxmA[4] = {vxm.x, vxm.y, vxm.z, vxm.w};
    const float pxpA[4] = {pxp.x, pxp.y, pxp.z, pxp.w};
    const float pxmA[4] = {pxm.x, pxm.y, pxm.z, pxm.w};

    #pragma unroll
    for (int k = 0; k < 4; ++k) {
        const float dudx = (uxpA[k] - uxmA[k]) * 127.5f;   // scaled inputs
        const float dvdx = (vxpA[k] - vxmA[k]) * 127.5f;
        const float dpdx = (pxpA[k] - pxmA[k]) * sdx;      // raw p
        const float dudy = (ur[k] - ul[k]) * 127.5f;
        const float dvdy = (vr[k] - vl[k]) * 127.5f;
        const float dpdy = (pr[k] - pl[k]) * sdx;
        const float lapu = (uxpA[k] + uxmA[k] + ur[k] + ul[k]) * 0.65025f
                         - 2.601f * ucA[k];
        const float lapv = (vxpA[k] + vxmA[k] + vr[k] + vl[k]) * 0.65025f
                         - 2.601f * vcA[k];
        r0[k] = fabsf(dudx + dvdy);
        r1[k] = fabsf((unA[k] - umA[k]) * 32.0f + ucA[k] * dudx + vcA[k] * dudy
                      + dpdx - lapu);
        r2[k] = fabsf((vnA[k] - vmA[k]) * 32.0f + ucA[k] * dvdx + vcA[k] * dvdy
                      + dpdy - lapv);
    }
}

__global__ __launch_bounds__(512)
void ns_loss_kernel(const float* __restrict__ X, const float* __restrict__ Y,
                    const float* __restrict__ stdp, double* __restrict__ acc)
{
    __shared__ float stage[2][3][4][256];   // 24 KiB: [tensor][u,v,p][row][col]
    __shared__ float rxch[3][4][256];       // 12 KiB: X residual exchange
    __shared__ float smr[3][4];

    const float s   = *stdp;
    const float sdx = s * 127.5f;

    // XCD mapping: grp = orig&7 -> (b-chunk z, j-half jh); band = orig>>3.
    const int orig = blockIdx.x;
    const int grp  = orig & 7;
    const int band = orig >> 3;            // 0..127
    const int z    = grp >> 1;             // 0..3
    const int jh   = grp & 1;              // 0..1

    const int tid = threadIdx.x;
    const int tg  = tid >> 8;              // 0 = X-waves, 1 = Y-waves
    const int t8  = tid & 255;
    const int io  = t8 >> 6;               // row in band (wave-uniform)
    const int jt  = t8 & 63;               // f4-col in half-row
    const int jl  = jt << 2;               // 0..252
    const int j0g = (jh << 8) + jl;        // global float col
    const int irow = 1 + band * 4 + io;
    const int i    = min(irow, 511);
    const bool vrow = (irow <= 510);
    const int bs = 1 + 15 * z + (z == 3 ? 1 : 0);   // 1,16,31,47
    const int nsteps = (z < 2) ? 15 : 16;

    const float* __restrict__ T = tg ? Y : X;
    int c = bs * BSTR + i * Wd + j0g;
    const int eoff = (io == 0) ? -Wd : ((i < 511) ? Wd : 0);
    const bool isedge = (io == 0) || (io == 3);
    const int offL = (j0g == 0) ? 0 : -1;            // clamped; masked at k=0
    const int offR = (j0g == 508) ? 3 : 4;           // clamped; masked at k=3

    // ---- carried state (one tensor): 5 float4 = 20 VGPRs ----
    float4 um = scale4(ld4(T + c - BSTR), s);
    float4 uc = scale4(ld4(T + c), s);
    float4 vm = scale4(ld4(T + c - BSTR + CSTR), s);
    float4 vc = scale4(ld4(T + c + CSTR), s);
    float4 pc = ld4(T + c + 2 * CSTR);

    float s0 = 0.0f, s1 = 0.0f, s2 = 0.0f;

    for (int k = 0; k < nsteps; ++k) {
        // ---- fresh loads: plane b+1 (always exists: plane <= 63) ----
        const float4 unr = ld4(T + c + BSTR);
        const float4 vnr = ld4(T + c + BSTR + CSTR);
        const float4 pn  = ld4(T + c + BSTR + 2 * CSTR);
        // edge row + j-boundary scalars for plane k
        float4 eu = uc, ev = vc, ep = pc;            // dummies for io 1/2
        if (isedge) {
            eu = scale4(ld4(T + c + eoff), s);
            ev = scale4(ld4(T + c + CSTR + eoff), s);
            ep = ld4(T + c + 2 * CSTR + eoff);
        }
        float uL = 0, vL = 0, pL = 0, uR = 0, vR = 0, pR = 0;
        if (jt == 0) {
            uL = T[c + offL] * s; vL = T[c + CSTR + offL] * s;
            pL = T[c + 2 * CSTR + offL];
        }
        if (jt == 63) {
            uR = T[c + offR] * s; vR = T[c + CSTR + offR] * s;
            pR = T[c + 2 * CSTR + offR];
        }

        // ---- stage current plane (carried regs only; no load wait) ----
        *(float4*)&stage[tg][0][io][jl] = uc;
        *(float4*)&stage[tg][1][io][jl] = vc;
        *(float4*)&stage[tg][2][io][jl] = pc;
        asm volatile("s_waitcnt lgkmcnt(0)" ::: "memory");
        __builtin_amdgcn_s_barrier();     // globals stay in flight

        const float4 un = scale4(unr, s);
        const float4 vn = scale4(vnr, s);

        // ---- compute own-tensor residuals ----
        float r0[4], r1[4], r2[4];
        plane_resid(stage[tg], io, jt, jl, eu, ev, ep,
                    um, uc, un, vm, vc, vn, pc,
                    uL, vL, pL, uR, vR, pR, sdx, r0, r1, r2);

        // ---- X-waves publish residuals ----
        if (tg == 0) {
            #pragma unroll
            for (int kk = 0; kk < 4; ++kk) {
                rxch[0][io][jl + kk] = r0[kk];
                rxch[1][io][jl + kk] = r1[kk];
                rxch[2][io][jl + kk] = r2[kk];
            }
        }
        asm volatile("s_waitcnt lgkmcnt(0)" ::: "memory");
        __builtin_amdgcn_s_barrier();

        // ---- Y-waves accumulate (r_y - r_x)^2 ----
        if (tg == 1) {
            #pragma unroll
            for (int kk = 0; kk < 4; ++kk) {
                float e0 = r0[kk] - rxch[0][io][jl + kk];
                float e1 = r1[kk] - rxch[1][io][jl + kk];
                float e2 = r2[kk] - rxch[2][io][jl + kk];
                const bool dead = (!vrow) || (kk == 0 && j0g == 0)
                                          || (kk == 3 && j0g == 508);
                if (dead) { e0 = 0.0f; e1 = 0.0f; e2 = 0.0f; }
                s0 += e0 * e0; s1 += e1 * e1; s2 += e2 * e2;
            }
        }

        // ---- rotate chains (un->uc avoids reload) ----
        um = uc; uc = un; vm = vc; vc = vn; pc = pn;
        c += BSTR;
        // NOTE: rxch reads (above) are separated from next iter's X writes
        // by the stage barrier; stage reads are done before the rx barrier.
    }

    // ---- reduction: Y-waves only ----
    if (tg == 1) {
        for (int o = 32; o > 0; o >>= 1) {
            s0 += __shfl_down(s0, o);
            s1 += __shfl_down(s1, o);
            s2 += __shfl_down(s2, o);
        }
        if (jt == 0) { smr[0][io] = s0; smr[1][io] = s1; smr[2][io] = s2; }
    }
    __syncthreads();
    if (tid == 0) {
        atomicAdd(&acc[0], (double)smr[0][0] + (double)smr[0][1]
                         + (double)smr[0][2] + (double)smr[0][3]);
        atomicAdd(&acc[1], (double)smr[1][0] + (double)smr[1][1]
                         + (double)smr[1][2] + (double)smr[1][3]);
        atomicAdd(&acc[2], (double)smr[2][0] + (double)smr[2][1]
                         + (double)smr[2][2] + (double)smr[2][3]);
    }
}

__global__ void ns_finalize_kernel(const double* __restrict__ acc,
                                   float* __restrict__ out)
{
    if (threadIdx.x == 0) {
        const double N = 62.0 * 510.0 * 510.0;
        out[0] = (float)(1.0e-3 * (acc[0] + acc[1] + acc[2]) / N);
    }
}

extern "C" void kernel_launch(void* const* d_in, const int* in_sizes, int n_in,
                              void* d_out, int out_size, void* d_ws, size_t ws_size,
                              hipStream_t stream) {
    const float* X    = (const float*)d_in[0];
    const float* Y    = (const float*)d_in[1];
    const float* stdp = (const float*)d_in[2];
    float* out  = (float*)d_out;
    double* acc = (double*)d_ws;

    hipMemsetAsync(acc, 0, 3 * sizeof(double), stream);

    dim3 block(512);
    dim3 grid(1024);  // 8 XCD groups (z,jh) x 128 bands
    ns_loss_kernel<<<grid, block, 0, stream>>>(X, Y, stdp, acc);
    ns_finalize_kernel<<<1, 64, 0, stream>>>(acc, out);
}

// Round 20
// 123.379 us; speedup vs baseline: 1.3117x; 1.1397x over previous
//
#include <hip/hip_runtime.h>

// Navier-Stokes physics-informed loss (f32 in, scalar f32 out).
// x,y: (64,3,512,512). Interior: b in [1,62], i,j in [1,510].
// r0 = |dudx + dvdy| ; r1 = |dudt + u*dudx + v*dudy + dpdx - MU*lap u| ;
// r2 = |dvdt + u*dvdx + v*dvdy + dpdy - MU*lap v| ; dudt=(u[b+1]-u[b-1])*32
//
// TERMINAL KERNEL = R14 restored (best of 19 rounds: wall 124.3us).
// Structure: block = 512 thr = 4 i-rows x 128 float4-cols; b-march;
// u,v,p center rows staged to LDS FROM REGISTERS (carried for the b-march,
// zero reload); i+-1 from LDS (band edges from prefetched regs); j+-1 via
// shfl; ALL global loads prefetched one plane ahead; raw s_barrier +
// lgkmcnt(0) only, so prefetched global loads stay in flight across
// barriers (T14/T3 mechanism).
// Falsified levers (R15-R19): fewer barriers (R17 -10%), less LDS + more
// bytes (R18 -23%), 2-D wave tiling / shfl-sharing (R16 -24%), wave-split
// X/Y for 8-waves/SIMD tier (R19: occ 42% but VALUBusy unchanged ~31%,
// -10%) -> occupancy, barrier count, byte count each NOT binding here;
// the op sits at a VALU/DS-pipe/global-service balance point.

constexpr int Wd   = 512;
constexpr int CSTR = 512 * 512;
constexpr int BSTR = 3 * 512 * 512;

__device__ __forceinline__ float4 ld4(const float* p) {
    return *reinterpret_cast<const float4*>(p);
}
__device__ __forceinline__ float4 scale4(float4 a, float s) {
    return make_float4(a.x * s, a.y * s, a.z * s, a.w * s);
}

// Residuals for one tensor at the current plane.
// L: this tensor's LDS slab [field u,v,p][row 0..3][512 floats].
// eu,ev: SCALED edge row; ep RAW. mu,cu,nus: u at b-1,b,b+1 (all SCALED).
// cp: RAW own p center row.
__device__ __forceinline__ void plane_resid(
    const float (&L)[3][4][512],
    int io, int jt, int j0,
    float4 eu, float4 ev, float4 ep,
    float4 mu, float4 cu, float4 nus,
    float4 mv, float4 cv, float4 nvs,
    float4 cp, float sdx,
    float r0[4], float r1[4], float r2[4])
{
    float4 uxm, vxm, pxm, uxp, vxp, pxp;
    if (io == 0) { uxm = eu; vxm = ev; pxm = ep; }
    else {
        uxm = ld4(&L[0][io - 1][j0]);
        vxm = ld4(&L[1][io - 1][j0]);
        pxm = ld4(&L[2][io - 1][j0]);
    }
    if (io == 3) { uxp = eu; vxp = ev; pxp = ep; }
    else {
        uxp = ld4(&L[0][io + 1][j0]);
        vxp = ld4(&L[1][io + 1][j0]);
        pxp = ld4(&L[2][io + 1][j0]);
    }

    // j-neighbors: shfl on carried center regs; wave-boundary from LDS.
    float u_l = __shfl_up(cu.w, 1);
    float v_l = __shfl_up(cv.w, 1);
    float p_l = __shfl_up(cp.w, 1);
    float u_r = __shfl_down(cu.x, 1);
    float v_r = __shfl_down(cv.x, 1);
    float p_r = __shfl_down(cp.x, 1);
    const int lane = jt & 63;
    if (lane == 0) {                       // needs col j0-1 (masked if j0==0)
        const int jm = (j0 == 0) ? 0 : (j0 - 1);
        u_l = L[0][io][jm]; v_l = L[1][io][jm]; p_l = L[2][io][jm];
    }
    if (lane == 63) {                      // needs col j0+4 (masked at j0==508)
        const int jp = (j0 >= 508) ? 511 : (j0 + 4);
        u_r = L[0][io][jp]; v_r = L[1][io][jp]; p_r = L[2][io][jp];
    }

    const float ucA[4] = {cu.x, cu.y, cu.z, cu.w};
    const float vcA[4] = {cv.x, cv.y, cv.z, cv.w};
    const float umA[4] = {mu.x, mu.y, mu.z, mu.w};
    const float vmA[4] = {mv.x, mv.y, mv.z, mv.w};
    const float unA[4] = {nus.x, nus.y, nus.z, nus.w};
    const float vnA[4] = {nvs.x, nvs.y, nvs.z, nvs.w};
    const float ul[4]  = {u_l, cu.x, cu.y, cu.z};
    const float ur[4]  = {cu.y, cu.z, cu.w, u_r};
    const float vl[4]  = {v_l, cv.x, cv.y, cv.z};
    const float vr[4]  = {cv.y, cv.z, cv.w, v_r};
    const float pl[4]  = {p_l, cp.x, cp.y, cp.z};
    const float pr[4]  = {cp.y, cp.z, cp.w, p_r};
    const float uxpA[4] = {uxp.x, uxp.y, uxp.z, uxp.w};
    const float uxmA[4] = {uxm.x, uxm.y, uxm.z, uxm.w};
    const float vxpA[4] = {vxp.x, vxp.y, vxp.z, vxp.w};
    const float vxmA[4] = {vxm.x, vxm.y, vxm.z, vxm.w};
    const float pxpA[4] = {pxp.x, pxp.y, pxp.z, pxp.w};
    const float pxmA[4] = {pxm.x, pxm.y, pxm.z, pxm.w};

    #pragma unroll
    for (int k = 0; k < 4; ++k) {
        const float dudx = (uxpA[k] - uxmA[k]) * 127.5f;   // scaled inputs
        const float dvdx = (vxpA[k] - vxmA[k]) * 127.5f;
        const float dpdx = (pxpA[k] - pxmA[k]) * sdx;      // raw p
        const float dudy = (ur[k] - ul[k]) * 127.5f;
        const float dvdy = (vr[k] - vl[k]) * 127.5f;
        const float dpdy = (pr[k] - pl[k]) * sdx;
        const float lapu = (uxpA[k] + uxmA[k] + ur[k] + ul[k]) * 0.65025f
                         - 2.601f * ucA[k];
        const float lapv = (vxpA[k] + vxmA[k] + vr[k] + vl[k]) * 0.65025f
                         - 2.601f * vcA[k];
        r0[k] = fabsf(dudx + dvdy);
        r1[k] = fabsf((unA[k] - umA[k]) * 32.0f + ucA[k] * dudx + vcA[k] * dudy
                      + dpdx - lapu);
        r2[k] = fabsf((vnA[k] - vmA[k]) * 32.0f + ucA[k] * dvdx + vcA[k] * dvdy
                      + dpdy - lapv);
    }
}

__global__ __launch_bounds__(512)
void ns_loss_kernel(const float* __restrict__ X, const float* __restrict__ Y,
                    const float* __restrict__ stdp, double* __restrict__ acc)
{
    __shared__ float lds[2][3][4][512];     // 48 KiB: [tensor][u,v,p][row][col]
    __shared__ float smr[3][8];

    const float s   = *stdp;
    const float sdx = s * 127.5f;

    // XCD swizzle: nwg = 512 = 8*64; z-major, band-minor.
    const int orig = blockIdx.x;
    const int wg   = (orig & 7) * 64 + (orig >> 3);
    const int z    = wg >> 7;              // b-chunk 0..3 (15,15,16,16 planes)
    const int band = wg & 127;             // i-band 0..127

    const int tid = threadIdx.x;
    const int io  = tid >> 7;              // row within band, 0..3
    const int jt  = tid & 127;             // float4-column thread
    const int j0  = jt << 2;
    const int irow = 1 + band * 4 + io;
    const int i    = min(irow, 511);
    const bool vrow = (irow <= 510);
    const int bs = 1 + 15 * z + (z == 3 ? 1 : 0);   // 1,16,31,47
    const int nsteps = (z < 2) ? 15 : 16;

    int c = bs * BSTR + i * Wd + j0;
    const int cup  = (i < 511) ? Wd : 0;
    const int eoff = (io == 0) ? -Wd : cup;          // edge-row offset
    const bool isedge = (io == 0) || (io == 3);

    // ---- prologue: plane bs ----
    float4 xmu = scale4(ld4(X + c - BSTR), s);
    float4 xcu = scale4(ld4(X + c), s);
    float4 xmv = scale4(ld4(X + c - BSTR + CSTR), s);
    float4 xcv = scale4(ld4(X + c + CSTR), s);
    float4 ymu = scale4(ld4(Y + c - BSTR), s);
    float4 ycu = scale4(ld4(Y + c), s);
    float4 ymv = scale4(ld4(Y + c - BSTR + CSTR), s);
    float4 ycv = scale4(ld4(Y + c + CSTR), s);
    float4 xnu = ld4(X + c + BSTR);                 // raw u(b+1)
    float4 xnv = ld4(X + c + BSTR + CSTR);
    float4 xcp = ld4(X + c + 2 * CSTR);             // raw p center
    float4 ynu = ld4(Y + c + BSTR);
    float4 ynv = ld4(Y + c + BSTR + CSTR);
    float4 ycp = ld4(Y + c + 2 * CSTR);
    float4 xeu = make_float4(0,0,0,0), xev = xeu, xep = xeu;
    float4 yeu = xeu, yev = xeu, yep = xeu;
    if (isedge) {
        xeu = scale4(ld4(X + c + eoff), s);
        xev = scale4(ld4(X + c + CSTR + eoff), s);
        xep = ld4(X + c + 2 * CSTR + eoff);
        yeu = scale4(ld4(Y + c + eoff), s);
        yev = scale4(ld4(Y + c + CSTR + eoff), s);
        yep = ld4(Y + c + 2 * CSTR + eoff);
    }

    float s0 = 0.0f, s1 = 0.0f, s2 = 0.0f;

    for (int it = 0; it < nsteps; ++it) {
        const int cn = c + ((it + 1 < nsteps) ? BSTR : 0);

        // ---- 1. stage current plane from registers ----
        *(float4*)&lds[0][0][io][j0] = xcu;
        *(float4*)&lds[0][1][io][j0] = xcv;
        *(float4*)&lds[0][2][io][j0] = xcp;
        *(float4*)&lds[1][0][io][j0] = ycu;
        *(float4*)&lds[1][1][io][j0] = ycv;
        *(float4*)&lds[1][2][io][j0] = ycp;
        asm volatile("s_waitcnt lgkmcnt(0)" ::: "memory");
        __builtin_amdgcn_s_barrier();     // raw: prefetched globals stay in flight

        // ---- 2. snapshot b+1 centers (frees xnu/xnv), issue next prefetch ----
        const float4 xnus = scale4(xnu, s), xnvs = scale4(xnv, s);
        const float4 ynus = scale4(ynu, s), ynvs = scale4(ynv, s);
        xnu = ld4(X + cn + BSTR);                    // u(p+2)
        xnv = ld4(X + cn + BSTR + CSTR);
        ynu = ld4(Y + cn + BSTR);
        ynv = ld4(Y + cn + BSTR + CSTR);
        float4 xcp2 = ld4(X + cn + 2 * CSTR);        // p(p+1)
        float4 ycp2 = ld4(Y + cn + 2 * CSTR);
        float4 xeu2 = xeu, xev2 = xev, xep2 = xep;
        float4 yeu2 = yeu, yev2 = yev, yep2 = yep;
        if (isedge) {
            xeu2 = scale4(ld4(X + cn + eoff), s);
            xev2 = scale4(ld4(X + cn + CSTR + eoff), s);
            xep2 = ld4(X + cn + 2 * CSTR + eoff);
            yeu2 = scale4(ld4(Y + cn + eoff), s);
            yev2 = scale4(ld4(Y + cn + CSTR + eoff), s);
            yep2 = ld4(Y + cn + 2 * CSTR + eoff);
        }

        // ---- 3. compute from LDS + regs ----
        float r0x[4], r1x[4], r2x[4], r0y[4], r1y[4], r2y[4];
        plane_resid(lds[0], io, jt, j0, xeu, xev, xep,
                    xmu, xcu, xnus, xmv, xcv, xnvs, xcp, sdx, r0x, r1x, r2x);
        plane_resid(lds[1], io, jt, j0, yeu, yev, yep,
                    ymu, ycu, ynus, ymv, ycv, ynvs, ycp, sdx, r0y, r1y, r2y);

        // ---- 4. accumulate (masked) ----
        #pragma unroll
        for (int k = 0; k < 4; ++k) {
            float e0 = r0y[k] - r0x[k];
            float e1 = r1y[k] - r1x[k];
            float e2 = r2y[k] - r2x[k];
            const bool dead = (!vrow) || (k == 0 && j0 == 0)
                                      || (k == 3 && j0 == 508);
            if (dead) { e0 = 0.0f; e1 = 0.0f; e2 = 0.0f; }
            s0 += e0 * e0; s1 += e1 * e1; s2 += e2 * e2;
        }

        __syncthreads();   // all LDS reads done before next iter's writes

        // ---- advance carries ----
        xmu = xcu; xcu = xnus; xmv = xcv; xcv = xnvs;
        ymu = ycu; ycu = ynus; ymv = ycv; ycv = ynvs;
        xcp = xcp2; ycp = ycp2;
        xeu = xeu2; xev = xev2; xep = xep2;
        yeu = yeu2; yev = yev2; yep = yep2;
        c = cn;
    }

    // ---- reduction: wave shuffle -> LDS -> f64 atomic ----
    for (int o = 32; o > 0; o >>= 1) {
        s0 += __shfl_down(s0, o);
        s1 += __shfl_down(s1, o);
        s2 += __shfl_down(s2, o);
    }
    const int wid = tid >> 6, lane = tid & 63;
    if (lane == 0) { smr[0][wid] = s0; smr[1][wid] = s1; smr[2][wid] = s2; }
    __syncthreads();
    if (tid == 0) {
        double t0 = 0, t1 = 0, t2 = 0;
        #pragma unroll
        for (int w = 0; w < 8; ++w) {
            t0 += (double)smr[0][w];
            t1 += (double)smr[1][w];
            t2 += (double)smr[2][w];
        }
        atomicAdd(&acc[0], t0);
        atomicAdd(&acc[1], t1);
        atomicAdd(&acc[2], t2);
    }
}

__global__ void ns_finalize_kernel(const double* __restrict__ acc,
                                   float* __restrict__ out)
{
    if (threadIdx.x == 0) {
        const double N = 62.0 * 510.0 * 510.0;
        out[0] = (float)(1.0e-3 * (acc[0] + acc[1] + acc[2]) / N);
    }
}

extern "C" void kernel_launch(void* const* d_in, const int* in_sizes, int n_in,
                              void* d_out, int out_size, void* d_ws, size_t ws_size,
                              hipStream_t stream) {
    const float* X    = (const float*)d_in[0];
    const float* Y    = (const float*)d_in[1];
    const float* stdp = (const float*)d_in[2];
    float* out  = (float*)d_out;
    double* acc = (double*)d_ws;

    hipMemsetAsync(acc, 0, 3 * sizeof(double), stream);

    dim3 block(512);
    dim3 grid(512);   // 128 i-bands x 4 b-chunks; 2 blk/CU -> single round
    ns_loss_kernel<<<grid, block, 0, stream>>>(X, Y, stdp, acc);
    ns_finalize_kernel<<<1, 64, 0, stream>>>(acc, out);
}